// Round 10
// baseline (275.642 us; speedup 1.0000x reference)
//
#include <hip/hip_runtime.h>

// ---------------------------------------------------------------------------
// TasteGNN (fp32 storage, bf16-quantized values):
//   h_ing = x_ing@W_ing+b; GAT edge softmax over dst segments; weighted
//   scatter-agg; relu; (semantic attn over 1 metapath == 1.0, skipped);
//   residual blend 0.5/0.5. out_ing = x_ing passthrough.
//
// HARNESS FACTS:
//   - float tensors are FP32 in memory (r0-3 forensics).
//   - d_ws is POISON-RACED: must NOT be used (R7 forensics).
//   - cg::grid_group::sync() costs ~150us/sync (R13). Launches are ~us-cheap.
//   - ~170us of the timed region is harness poison/restore fills.
//
// R16: k_agg made persistent (grid-stride, 1024 blocks): R15 profile showed
// OccupancyPercent 28% with VGPR=52/no-LDS => wave-churn, not residency;
// each wave did 4 dsts and exited. Now each wave loops ~3 jobs with the
// NEXT job's offsets prefetched before the current body (hides the serial
// offsets->indices->gather chain head under phase B of the previous job).
// k_gemm (LDS Wt + LDS-staged coalesced H-store) unchanged from R15.
//
// Memory plan (all inside d_out, no d_ws dependence):
//   bytes [0, 25.6MB)      : h_ing staged as bf16 (ushort), read by k_agg
//   bytes [26MB, ~29.7MB)  : scratch (a_src, CSR arrays, Wt, u, v, cvals)
//   bytes [51.2MB, 76.8MB) : out_taste (fp32, final output region 1)
//   rows >= 61440 of region 0 written by k_gemm passthrough;
//   final op: copy fp32 x_ing rows [0, 61440) over bytes [0, 31.46MB)
// ---------------------------------------------------------------------------

typedef __attribute__((ext_vector_type(8))) short short8;   // 8 x bf16
typedef __attribute__((ext_vector_type(4))) float f32x4;

__device__ __forceinline__ float b2f(unsigned short u) {
    return __uint_as_float(((unsigned int)u) << 16);
}
__device__ __forceinline__ unsigned short f2b(float f) {
    unsigned int x = __float_as_uint(f);
    x += 0x7fffu + ((x >> 16) & 1u);   // RNE; exact for bf16-quantized values
    return (unsigned short)(x >> 16);
}

#define D 128
#define SPLIT_ROW 61440   // rows >= this: passthrough fused into k_gemm

__device__ __forceinline__ void acc8(float* acc, float w, uint4 h) {
    acc[0] += w * b2f((unsigned short)(h.x & 0xffffu));
    acc[1] += w * b2f((unsigned short)(h.x >> 16));
    acc[2] += w * b2f((unsigned short)(h.y & 0xffffu));
    acc[3] += w * b2f((unsigned short)(h.y >> 16));
    acc[4] += w * b2f((unsigned short)(h.z & 0xffffu));
    acc[5] += w * b2f((unsigned short)(h.z >> 16));
    acc[6] += w * b2f((unsigned short)(h.w & 0xffffu));
    acc[7] += w * b2f((unsigned short)(h.w >> 16));
}

// --- prep (325 blocks): b<64 transpose W_ing->Wt(bf16); 64<=b<129: 260
//     waves of lane-parallel length-128 dots (u, v, cvals); b>=129: zero
//     the counts array (absorbs the old hipMemsetAsync dispatch).
__global__ __launch_bounds__(256) void k_prep(
        const float* __restrict__ W_ing,  const float* __restrict__ b_ing,
        const float* __restrict__ W_taste,const float* __restrict__ b_taste,
        const float* __restrict__ att_src,const float* __restrict__ att_dst,
        unsigned short* __restrict__ Wt,
        float* __restrict__ u, float* __restrict__ v, float* __restrict__ cvals,
        int* __restrict__ counts, int NT)
{
    int tid = threadIdx.x;
    if (blockIdx.x >= 129) {                     // zero counts
        int idx = (blockIdx.x - 129) * 256 + tid;
        if (idx < NT) counts[idx] = 0;
        return;
    }
    if (blockIdx.x < 64) {                       // transpose + bf16 convert
        int idx = blockIdx.x * 256 + tid;        // 64*256 = 16384 = all elems
        int k = idx >> 7, j = idx & 127;
        Wt[j * D + k] = f2b(W_ing[idx]);
        return;
    }
    int gw = (blockIdx.x - 64) * 4 + (tid >> 6);
    int lane = tid & 63;
    const float* row; const float* vec; float* dst;
    if (gw < 128)      { row = W_ing   + (size_t)gw * D;         vec = att_src; dst = u + gw; }
    else if (gw < 256) { row = W_taste + (size_t)(gw - 128) * D; vec = att_dst; dst = v + (gw - 128); }
    else if (gw == 256){ row = b_ing;   vec = att_src; dst = cvals; }
    else if (gw == 257){ row = b_taste; vec = att_dst; dst = cvals + 1; }
    else return;
    float2 a = *(const float2*)(row + lane * 2);
    float2 w = *(const float2*)(vec + lane * 2);
    float s = a.x * w.x + a.y * w.y;
#pragma unroll
    for (int off = 32; off; off >>= 1) s += __shfl_xor(s, off);
    if (lane == 0) *dst = s;
}

// --- histogram of dst ------------------------------------------------------
__global__ __launch_bounds__(256) void k_hist(const int* __restrict__ dst,
                                              int* __restrict__ counts, int E)
{
    int e = blockIdx.x * 256 + threadIdx.x;
    if (e < E) atomicAdd(&counts[dst[e]], 1);
}

// --- 3-phase scan: A) per-block sums  B) scan sums  C) block scan + prefix -
__global__ __launch_bounds__(256) void k_scanA(const int* __restrict__ counts,
                                               int* __restrict__ blocksums, int n)
{
    __shared__ int lds[256];
    int tid = threadIdx.x;
    int i = blockIdx.x * 256 + tid;
    lds[tid] = (i < n) ? counts[i] : 0;
    __syncthreads();
#pragma unroll
    for (int off = 128; off > 0; off >>= 1) {
        if (tid < off) lds[tid] += lds[tid + off];
        __syncthreads();
    }
    if (tid == 0) blocksums[blockIdx.x] = lds[0];
}

__global__ __launch_bounds__(256) void k_scanB(const int* __restrict__ blocksums,
                                               int* __restrict__ blockpre,
                                               int* __restrict__ offsets,
                                               int nb, int n)
{
    __shared__ int lds[256];
    int tid = threadIdx.x;
    int v = (tid < nb) ? blocksums[tid] : 0;
    lds[tid] = v;
    __syncthreads();
#pragma unroll
    for (int off = 1; off < 256; off <<= 1) {
        int t = (tid >= off) ? lds[tid - off] : 0;
        __syncthreads();
        lds[tid] += t;
        __syncthreads();
    }
    if (tid < nb) blockpre[tid] = lds[tid] - v;   // exclusive prefix
    if (tid == 255) offsets[n] = lds[255];        // total
}

__global__ __launch_bounds__(256) void k_scanC(const int* __restrict__ counts,
                                               const int* __restrict__ blockpre,
                                               int* __restrict__ offsets,
                                               int* __restrict__ cursor, int n)
{
    __shared__ int lds[256];
    int tid = threadIdx.x;
    int i = blockIdx.x * 256 + tid;
    int v = (i < n) ? counts[i] : 0;
    lds[tid] = v;
    __syncthreads();
#pragma unroll
    for (int off = 1; off < 256; off <<= 1) {
        int t = (tid >= off) ? lds[tid - off] : 0;
        __syncthreads();
        lds[tid] += t;
        __syncthreads();
    }
    if (i < n) {
        int o = blockpre[blockIdx.x] + lds[tid] - v;   // exclusive
        offsets[i] = o;
        cursor[i] = o;
    }
}

// --- scatter: src indices sorted by dst ------------------------------------
__global__ __launch_bounds__(256) void k_scatter(const int* __restrict__ dst,
                                                 const int* __restrict__ srcix,
                                                 int* __restrict__ cursor,
                                                 int* __restrict__ src_sorted, int E)
{
    int e = blockIdx.x * 256 + threadIdx.x;
    if (e < E) {
        int d = dst[e];
        int pos = atomicAdd(&cursor[d], 1);
        src_sorted[pos] = srcix[e];
    }
}

// --- GEMM: H(bf16) = X(fp32) @ W + b, bf16 MFMA 16x16x32 -------------------
// R12: Wt staged to LDS in [nt][ks][t][q] 16B-slot layout. A wave's B-read
// for (nt,ks) is 64 lanes reading a permutation of 64 consecutive 16B slots.
// R15: epilogue stages the C-tile through LDS (WtL reused after a barrier):
// 32 scattered 2B stores -> 4 coalesced 1KB stores per wave.
__global__ __launch_bounds__(256) void k_gemm(const float* __restrict__ X,
                                              const unsigned short* __restrict__ Wt,
                                              const float* __restrict__ bvec,
                                              const float* __restrict__ u,
                                              const float* __restrict__ cvals,
                                              unsigned short* __restrict__ H,
                                              float* __restrict__ a_srcv,
                                              float* __restrict__ outX, int M)
{
    __shared__ unsigned short WtL[D * D];   // 32KB
    int tid = threadIdx.x;

    // cooperative stage: 2048 16B-chunks, 8 per thread, coalesced reads
    {
        const uint4* wsrc = (const uint4*)Wt;
        uint4* wdst = (uint4*)WtL;
#pragma unroll
        for (int i = 0; i < 8; ++i) {
            int idx = i * 256 + tid;           // 16B-chunk index
            int j = idx >> 4, k8 = idx & 15;
            wdst[((j >> 4) * 4 + (k8 >> 2)) * 64 + (j & 15) * 4 + (k8 & 3)] = wsrc[idx];
        }
    }

    int wave = tid >> 6;
    int lane = tid & 63;
    int q = lane >> 4;       // quad
    int t = lane & 15;
    int lof = t * 4 + q;     // lane's slot offset within a 64-slot group
    long mbase = (long)blockIdx.x * 64 + wave * 16;
    long row = mbase + t; if (row >= M) row = M - 1;   // clamp: dup writes ok
    const float* A = X + row * D;

    // issue ALL A-loads first — single exposed HBM latency for the wave
    float4 a[8];
#pragma unroll
    for (int ks = 0; ks < 4; ++ks) {
        int ko = ks * 32 + q * 8;
        a[2 * ks]     = *(const float4*)(A + ko);
        a[2 * ks + 1] = *(const float4*)(A + ko + 4);
    }

    // passthrough out_ing for rows above the scratch region
    if (row >= SPLIT_ROW) {
        float* O = outX + row * D;
#pragma unroll
        for (int ks = 0; ks < 4; ++ks) {
            int ko = ks * 32 + q * 8;
            *(float4*)(O + ko)     = a[2 * ks];
            *(float4*)(O + ko + 4) = a[2 * ks + 1];
        }
    }

    // a_src = x.u + c0 (each lane: 32-col slice; reduce across 4 quads)
    float adot = 0.f;
#pragma unroll
    for (int ks = 0; ks < 4; ++ks) {
        int ko = ks * 32 + q * 8;
        const float* up = u + ko;
        float4 fa = a[2 * ks], fb = a[2 * ks + 1];
        adot += fa.x*up[0] + fa.y*up[1] + fa.z*up[2] + fa.w*up[3]
              + fb.x*up[4] + fb.y*up[5] + fb.z*up[6] + fb.w*up[7];
    }
    adot += __shfl_xor(adot, 16); adot += __shfl_xor(adot, 32);
    if (q == 0) a_srcv[row] = adot + cvals[0];

    // bf16 A-fragments
    short8 af[4];
#pragma unroll
    for (int ks = 0; ks < 4; ++ks) {
        float4 fa = a[2 * ks], fb = a[2 * ks + 1];
        short8 f;
        f[0]=f2b(fa.x); f[1]=f2b(fa.y); f[2]=f2b(fa.z); f[3]=f2b(fa.w);
        f[4]=f2b(fb.x); f[5]=f2b(fb.y); f[6]=f2b(fb.z); f[7]=f2b(fb.w);
        af[ks] = f;
    }

    __syncthreads();   // Wt staging complete (placed late: staging overlaps A)

    f32x4 acc[8];
#pragma unroll
    for (int j = 0; j < 8; ++j) acc[j] = (f32x4){0.f, 0.f, 0.f, 0.f};

    const short8* WtS = (const short8*)WtL;
#pragma unroll
    for (int ks = 0; ks < 4; ++ks) {
#pragma unroll
        for (int nt = 0; nt < 8; ++nt) {
            short8 bfr = WtS[(nt * 4 + ks) * 64 + lof];
            acc[nt] = __builtin_amdgcn_mfma_f32_16x16x32_bf16(af[ks], bfr, acc[nt], 0, 0, 0);
        }
    }

    // --- epilogue: stage C-tile in LDS, store coalesced --------------------
    // C/D frag: col(n) = lane&15, row(m) = quad*4 + reg   [verified m89/m91]
    __syncthreads();   // all waves done reading WtL -> safe to reuse
    {
        unsigned short* myH = WtL + wave * 16 * D;   // private 4KB slice
#pragma unroll
        for (int r = 0; r < 4; ++r) {
#pragma unroll
            for (int nt = 0; nt < 8; ++nt) {
                myH[(q * 4 + r) * D + nt * 16 + t] = f2b(acc[nt][r] + bvec[nt * 16 + t]);
            }
        }
        // no barrier: wave reads back only its own slice (lgkmcnt orders it)
        const uint4* src4 = (const uint4*)myH;
#pragma unroll
        for (int i = 0; i < 4; ++i) {
            int idx = i * 64 + lane;                 // uint4 idx in 4KB slice
            long orow = mbase + i * 4 + (lane >> 4); // = (idx*16B)/256B
            if (orow < M) {
                *(uint4*)(H + orow * D + (lane & 15) * 8) = src4[idx];
            }
        }
    }
}

// --- per-dst: segment softmax + weighted agg + relu + residual -------------
// 4 dsts per wave-job (16-lane groups); R16: persistent grid-stride waves,
// next job's offsets prefetched before the current body. Per job: batch-0
// H-rows prefetch before the softmax chain; phase B is a 2-deep software
// pipeline with x4-padded unconditional loads (invalid lanes: mys=0 ->
// safe row-0 load, myw=0 -> zero contribution).
__global__ __launch_bounds__(256) void k_agg(const int* __restrict__ offsets,
                                             const int* __restrict__ src_sorted,
                                             const float* __restrict__ a_src,
                                             const unsigned short* __restrict__ H,
                                             const float* __restrict__ x_taste,
                                             const float* __restrict__ v,
                                             const float* __restrict__ cvals,
                                             float* __restrict__ out_taste,
                                             int Nt)
{
    int lane = threadIdx.x & 63;
    int g = lane >> 4, gl = lane & 15, gbase = g * 16;
    int wid0 = (blockIdx.x * 256 + threadIdx.x) >> 6;   // global wave id
    int nw = gridDim.x * 4;                             // total waves
    int njobs = (Nt + 3) >> 2;
    if (wid0 >= njobs) return;

    float c1 = cvals[1];

    // current job state (prefetched across iterations)
    int job = wid0;
    int d = job * 4 + g;
    bool val = d < Nt;
    int dc = val ? d : (Nt - 1);
    int s_cur = offsets[dc], e_cur = offsets[dc + 1];

    while (true) {
        // ---- prefetch NEXT job's offsets (hides chain head under body) ----
        int jn = job + nw;
        bool jvalid = jn < njobs;
        int d_n = 0, dcn = 0; bool val_n = false;
        int s_nxt = 0, e_nxt = 0;
        if (jvalid) {
            d_n = jn * 4 + g;
            val_n = d_n < Nt;
            dcn = val_n ? d_n : (Nt - 1);
            s_nxt = offsets[dcn];
            e_nxt = offsets[dcn + 1];
        }

        // ---- body for current job (d=dc, start=s_cur, end=e_cur) ----------
        int start = s_cur, end = e_cur;
        int deg = end - start;
        bool has = (gl < deg);

        int mys = 0;
        if (has) mys = src_sorted[start + gl];

        // prefetch batch-0 H rows NOW — overlaps the entire softmax chain
        int ps0 = __shfl(mys, gbase + 0), ps1 = __shfl(mys, gbase + 1);
        int ps2 = __shfl(mys, gbase + 2), ps3 = __shfl(mys, gbase + 3);
        uint4 A0 = *(const uint4*)(H + (long)ps0 * D + gl * 8);
        uint4 A1 = *(const uint4*)(H + (long)ps1 * D + gl * 8);
        uint4 A2 = *(const uint4*)(H + (long)ps2 * D + gl * 8);
        uint4 A3 = *(const uint4*)(H + (long)ps3 * D + gl * 8);

        // x_taste row slice (8 floats/lane) -- reused for residual at the end
        const float* xrow = x_taste + (long)dc * D + gl * 8;
        float4 xa = *(const float4*)xrow;
        float4 xb = *(const float4*)(xrow + 4);

        // a_dst = x_taste[d] . v + c1  (fused; group-local 16-lane xor reduce)
        const float* vp = v + gl * 8;
        float s = xa.x*vp[0] + xa.y*vp[1] + xa.z*vp[2] + xa.w*vp[3]
                + xb.x*vp[4] + xb.y*vp[5] + xb.z*vp[6] + xb.w*vp[7];
        s += __shfl_xor(s, 1); s += __shfl_xor(s, 2);
        s += __shfl_xor(s, 4); s += __shfl_xor(s, 8);
        float ad = s + c1;

        // phase A: lane-parallel logits (first 16 edges held in registers)
        float myl = 0.f;
        if (has) {
            float l = a_src[mys] + ad;
            myl = l > 0.f ? l : 0.2f * l;
        }
        float m = has ? myl : -3.4e38f;
        for (int base = start + 16; base < end; base += 16) {   // deg>16: ~10%
            int e = base + gl;
            if (e < end) {
                float l = a_src[src_sorted[e]] + ad;
                l = l > 0.f ? l : 0.2f * l;
                m = fmaxf(m, l);
            }
        }
        m = fmaxf(m, __shfl_xor(m, 1)); m = fmaxf(m, __shfl_xor(m, 2));
        m = fmaxf(m, __shfl_xor(m, 4)); m = fmaxf(m, __shfl_xor(m, 8));

        float ssum = has ? __expf(myl - m) : 0.f;
        for (int base = start + 16; base < end; base += 16) {   // deg>16: ~10%
            int e = base + gl;
            if (e < end) {
                float l = a_src[src_sorted[e]] + ad;
                l = l > 0.f ? l : 0.2f * l;
                ssum += __expf(l - m);
            }
        }
        ssum += __shfl_xor(ssum, 1); ssum += __shfl_xor(ssum, 2);
        ssum += __shfl_xor(ssum, 4); ssum += __shfl_xor(ssum, 8);
        float inv = 1.0f / (ssum + 1e-16f);
        float myw = has ? __expf(myl - m) * inv : 0.f;

        // phase B: 2-deep pipelined gather-accumulate over x4-padded edges
        float acc[8];
#pragma unroll
        for (int j = 0; j < 8; ++j) acc[j] = 0.f;

        int dfirst = deg < 16 ? deg : 16;
        int dpad = (dfirst + 3) & ~3;          // 0,4,8,12,16

        for (int i = 0; i < dpad; i += 4) {
            float w0 = __shfl(myw, gbase + i),     w1 = __shfl(myw, gbase + i + 1);
            float w2 = __shfl(myw, gbase + i + 2), w3 = __shfl(myw, gbase + i + 3);
            int inext = i + 4;
            bool more = inext < dpad;
            uint4 B0, B1, B2, B3;
            if (more) {
                int t0 = __shfl(mys, gbase + inext),     t1 = __shfl(mys, gbase + inext + 1);
                int t2 = __shfl(mys, gbase + inext + 2), t3 = __shfl(mys, gbase + inext + 3);
                B0 = *(const uint4*)(H + (long)t0 * D + gl * 8);
                B1 = *(const uint4*)(H + (long)t1 * D + gl * 8);
                B2 = *(const uint4*)(H + (long)t2 * D + gl * 8);
                B3 = *(const uint4*)(H + (long)t3 * D + gl * 8);
            }
            acc8(acc, w0, A0); acc8(acc, w1, A1);
            acc8(acc, w2, A2); acc8(acc, w3, A3);
            if (more) { A0 = B0; A1 = B1; A2 = B2; A3 = B3; }
        }

        for (int e = start + 16; e < end; ++e) {                // deg>16 tail
            int s0 = src_sorted[e];
            float l = a_src[s0] + ad;
            l = l > 0.f ? l : 0.2f * l;
            float w0 = __expf(l - m) * inv;
            uint4 h0 = *(const uint4*)(H + (long)s0 * D + gl * 8);
            acc8(acc, w0, h0);
        }

        if (val) {
            float4 oa, ob;
            oa.x = 0.5f * (fmaxf(acc[0], 0.f) + xa.x);
            oa.y = 0.5f * (fmaxf(acc[1], 0.f) + xa.y);
            oa.z = 0.5f * (fmaxf(acc[2], 0.f) + xa.z);
            oa.w = 0.5f * (fmaxf(acc[3], 0.f) + xa.w);
            ob.x = 0.5f * (fmaxf(acc[4], 0.f) + xb.x);
            ob.y = 0.5f * (fmaxf(acc[5], 0.f) + xb.y);
            ob.z = 0.5f * (fmaxf(acc[6], 0.f) + xb.z);
            ob.w = 0.5f * (fmaxf(acc[7], 0.f) + xb.w);
            float* orow = out_taste + (long)dc * D + gl * 8;
            *(float4*)orow       = oa;
            *(float4*)(orow + 4) = ob;
        }

        // ---- advance ------------------------------------------------------
        if (!jvalid) break;
        job = jn; d = d_n; val = val_n; dc = dcn;
        s_cur = s_nxt; e_cur = e_nxt;
    }
}

// --- passthrough copy: out_ing rows [0, SPLIT_ROW) (16B/thread) ------------
__global__ __launch_bounds__(256) void k_copy(const uint4* __restrict__ src,
                                              uint4* __restrict__ dst, long n16)
{
    long i = (long)blockIdx.x * 256 + threadIdx.x;
    long stride = (long)gridDim.x * 256;
    for (; i < n16; i += stride) dst[i] = src[i];
}

extern "C" void kernel_launch(void* const* d_in, const int* in_sizes, int n_in,
                              void* d_out, int out_size, void* d_ws, size_t ws_size,
                              hipStream_t stream)
{
    const float* x_ing   = (const float*)d_in[0];
    const float* x_taste = (const float*)d_in[1];
    const float* W_ing   = (const float*)d_in[2];
    const float* b_ing   = (const float*)d_in[3];
    const float* W_taste = (const float*)d_in[4];
    const float* b_taste = (const float*)d_in[5];
    const float* att_src = (const float*)d_in[6];
    const float* att_dst = (const float*)d_in[7];
    // d_in[8..10] = Wk, bk, q: dead (softmax over single metapath == 1.0)
    const int* src_idx = (const int*)d_in[11];
    const int* dst_idx = (const int*)d_in[12];

    const int NI = in_sizes[0] / D;   // 100000
    const int NT = in_sizes[1] / D;   // 50000
    const int E  = in_sizes[11];      // 600000

    float* out = (float*)d_out;
    float* out_taste = out + (size_t)NI * D;               // region 1 (fp32)
    unsigned short* h_ing = (unsigned short*)d_out;        // bytes [0,25.6MB)

    // scratch inside d_out at byte offset 26MB (wiped by final x_ing copy).
    // d_ws is NOT used: harness re-poison races our pipeline (R7 forensics).
    char* ws = (char*)d_out + (size_t)26 * 1024 * 1024;
    size_t off = 0;
    auto alloc = [&](size_t bytes) -> void* {
        void* p = ws + off;
        off = (off + bytes + 255) & ~(size_t)255;
        return p;
    };
    float* a_src     = (float*)alloc((size_t)NI * 4);
    int* counts      = (int*)alloc((size_t)NT * 4);
    int* cursor      = (int*)alloc((size_t)NT * 4);
    int* offsets     = (int*)alloc((size_t)(NT + 1) * 4);
    int* src_sorted  = (int*)alloc((size_t)E * 4);
    unsigned short* Wt = (unsigned short*)alloc((size_t)D * D * 2);
    float* u         = (float*)alloc(D * 4);
    float* v         = (float*)alloc(D * 4);
    float* cvals     = (float*)alloc(2 * 4);
    int* blocksums   = (int*)alloc(256 * 4);
    int* blockpre    = (int*)alloc(256 * 4);
    (void)d_ws; (void)ws_size; (void)out_size; (void)n_in;
    // scratch ends < 29.7MB < SPLIT_ROW*512 = 31.46MB  (passthrough-safe)

    const int nb = (NT + 255) / 256;   // 196 scan blocks

    // prep also zeroes counts (blocks 129..129+nb)
    k_prep<<<129 + nb, 256, 0, stream>>>(W_ing, b_ing, W_taste, b_taste,
                                         att_src, att_dst, Wt, u, v, cvals,
                                         counts, NT);

    k_hist<<<(E + 255) / 256, 256, 0, stream>>>(dst_idx, counts, E);
    k_scanA<<<nb, 256, 0, stream>>>(counts, blocksums, NT);
    k_scanB<<<1, 256, 0, stream>>>(blocksums, blockpre, offsets, nb, NT);
    k_scanC<<<nb, 256, 0, stream>>>(counts, blockpre, offsets, cursor, NT);
    k_scatter<<<(E + 255) / 256, 256, 0, stream>>>(dst_idx, src_idx, cursor, src_sorted, E);

    // gemm fuses a_src AND passthrough stores for rows >= SPLIT_ROW
    k_gemm<<<(NI + 63) / 64, 256, 0, stream>>>(x_ing, Wt, b_ing, u, cvals,
                                               h_ing, a_src, out, NI);

    // agg fuses a_dst = x_taste.(W_taste att_dst) + b_taste.att_dst
    // persistent grid-stride: 1024 blocks x 4 waves, ~3 jobs/wave
    k_agg<<<1024, 256, 0, stream>>>(offsets, src_sorted, a_src,
                                    h_ing, x_taste, v, cvals,
                                    out_taste, NT);

    // out_ing rows [0, SPLIT_ROW) — LAST op, wipes h_ing staging + scratch
    long n16 = ((long)SPLIT_ROW * D * 4) / 16;
    k_copy<<<2048, 256, 0, stream>>>((const uint4*)x_ing, (uint4*)out, n16);
}

// Round 11
// 270.089 us; speedup vs baseline: 1.0206x; 1.0206x over previous
//
#include <hip/hip_runtime.h>

// ---------------------------------------------------------------------------
// TasteGNN (fp32 storage, bf16-quantized values):
//   h_ing = x_ing@W_ing+b; GAT edge softmax over dst segments; weighted
//   scatter-agg; relu; (semantic attn over 1 metapath == 1.0, skipped);
//   residual blend 0.5/0.5. out_ing = x_ing passthrough.
//
// HARNESS FACTS:
//   - float tensors are FP32 in memory (r0-3 forensics).
//   - d_ws is POISON-RACED: must NOT be used (R7 forensics).
//   - cg::grid_group::sync() costs ~150us/sync (R13). Launches are ~us-cheap.
//   - ~170us of the timed region is harness poison/restore fills.
//   - k_agg occupancy (~28%) is NOT wave-churn: persistent grid-stride
//     (R16) left it unchanged and cost 5us in registers/loop state.
//
// R17 = R15 exactly (session best, 270.65us): k_agg non-persistent 2-deep,
// k_gemm LDS-Wt + LDS-staged coalesced H-store. R16's persistent k_agg
// reverted (falsified).
//
// Memory plan (all inside d_out, no d_ws dependence):
//   bytes [0, 25.6MB)      : h_ing staged as bf16 (ushort), read by k_agg
//   bytes [26MB, ~29.7MB)  : scratch (a_src, CSR arrays, Wt, u, v, cvals)
//   bytes [51.2MB, 76.8MB) : out_taste (fp32, final output region 1)
//   rows >= 61440 of region 0 written by k_gemm passthrough;
//   final op: copy fp32 x_ing rows [0, 61440) over bytes [0, 31.46MB)
// ---------------------------------------------------------------------------

typedef __attribute__((ext_vector_type(8))) short short8;   // 8 x bf16
typedef __attribute__((ext_vector_type(4))) float f32x4;

__device__ __forceinline__ float b2f(unsigned short u) {
    return __uint_as_float(((unsigned int)u) << 16);
}
__device__ __forceinline__ unsigned short f2b(float f) {
    unsigned int x = __float_as_uint(f);
    x += 0x7fffu + ((x >> 16) & 1u);   // RNE; exact for bf16-quantized values
    return (unsigned short)(x >> 16);
}

#define D 128
#define SPLIT_ROW 61440   // rows >= this: passthrough fused into k_gemm

__device__ __forceinline__ void acc8(float* acc, float w, uint4 h) {
    acc[0] += w * b2f((unsigned short)(h.x & 0xffffu));
    acc[1] += w * b2f((unsigned short)(h.x >> 16));
    acc[2] += w * b2f((unsigned short)(h.y & 0xffffu));
    acc[3] += w * b2f((unsigned short)(h.y >> 16));
    acc[4] += w * b2f((unsigned short)(h.z & 0xffffu));
    acc[5] += w * b2f((unsigned short)(h.z >> 16));
    acc[6] += w * b2f((unsigned short)(h.w & 0xffffu));
    acc[7] += w * b2f((unsigned short)(h.w >> 16));
}

// --- prep (325 blocks): b<64 transpose W_ing->Wt(bf16); 64<=b<129: 260
//     waves of lane-parallel length-128 dots (u, v, cvals); b>=129: zero
//     the counts array (absorbs the old hipMemsetAsync dispatch).
__global__ __launch_bounds__(256) void k_prep(
        const float* __restrict__ W_ing,  const float* __restrict__ b_ing,
        const float* __restrict__ W_taste,const float* __restrict__ b_taste,
        const float* __restrict__ att_src,const float* __restrict__ att_dst,
        unsigned short* __restrict__ Wt,
        float* __restrict__ u, float* __restrict__ v, float* __restrict__ cvals,
        int* __restrict__ counts, int NT)
{
    int tid = threadIdx.x;
    if (blockIdx.x >= 129) {                     // zero counts
        int idx = (blockIdx.x - 129) * 256 + tid;
        if (idx < NT) counts[idx] = 0;
        return;
    }
    if (blockIdx.x < 64) {                       // transpose + bf16 convert
        int idx = blockIdx.x * 256 + tid;        // 64*256 = 16384 = all elems
        int k = idx >> 7, j = idx & 127;
        Wt[j * D + k] = f2b(W_ing[idx]);
        return;
    }
    int gw = (blockIdx.x - 64) * 4 + (tid >> 6);
    int lane = tid & 63;
    const float* row; const float* vec; float* dst;
    if (gw < 128)      { row = W_ing   + (size_t)gw * D;         vec = att_src; dst = u + gw; }
    else if (gw < 256) { row = W_taste + (size_t)(gw - 128) * D; vec = att_dst; dst = v + (gw - 128); }
    else if (gw == 256){ row = b_ing;   vec = att_src; dst = cvals; }
    else if (gw == 257){ row = b_taste; vec = att_dst; dst = cvals + 1; }
    else return;
    float2 a = *(const float2*)(row + lane * 2);
    float2 w = *(const float2*)(vec + lane * 2);
    float s = a.x * w.x + a.y * w.y;
#pragma unroll
    for (int off = 32; off; off >>= 1) s += __shfl_xor(s, off);
    if (lane == 0) *dst = s;
}

// --- histogram of dst ------------------------------------------------------
__global__ __launch_bounds__(256) void k_hist(const int* __restrict__ dst,
                                              int* __restrict__ counts, int E)
{
    int e = blockIdx.x * 256 + threadIdx.x;
    if (e < E) atomicAdd(&counts[dst[e]], 1);
}

// --- 3-phase scan: A) per-block sums  B) scan sums  C) block scan + prefix -
__global__ __launch_bounds__(256) void k_scanA(const int* __restrict__ counts,
                                               int* __restrict__ blocksums, int n)
{
    __shared__ int lds[256];
    int tid = threadIdx.x;
    int i = blockIdx.x * 256 + tid;
    lds[tid] = (i < n) ? counts[i] : 0;
    __syncthreads();
#pragma unroll
    for (int off = 128; off > 0; off >>= 1) {
        if (tid < off) lds[tid] += lds[tid + off];
        __syncthreads();
    }
    if (tid == 0) blocksums[blockIdx.x] = lds[0];
}

__global__ __launch_bounds__(256) void k_scanB(const int* __restrict__ blocksums,
                                               int* __restrict__ blockpre,
                                               int* __restrict__ offsets,
                                               int nb, int n)
{
    __shared__ int lds[256];
    int tid = threadIdx.x;
    int v = (tid < nb) ? blocksums[tid] : 0;
    lds[tid] = v;
    __syncthreads();
#pragma unroll
    for (int off = 1; off < 256; off <<= 1) {
        int t = (tid >= off) ? lds[tid - off] : 0;
        __syncthreads();
        lds[tid] += t;
        __syncthreads();
    }
    if (tid < nb) blockpre[tid] = lds[tid] - v;   // exclusive prefix
    if (tid == 255) offsets[n] = lds[255];        // total
}

__global__ __launch_bounds__(256) void k_scanC(const int* __restrict__ counts,
                                               const int* __restrict__ blockpre,
                                               int* __restrict__ offsets,
                                               int* __restrict__ cursor, int n)
{
    __shared__ int lds[256];
    int tid = threadIdx.x;
    int i = blockIdx.x * 256 + tid;
    int v = (i < n) ? counts[i] : 0;
    lds[tid] = v;
    __syncthreads();
#pragma unroll
    for (int off = 1; off < 256; off <<= 1) {
        int t = (tid >= off) ? lds[tid - off] : 0;
        __syncthreads();
        lds[tid] += t;
        __syncthreads();
    }
    if (i < n) {
        int o = blockpre[blockIdx.x] + lds[tid] - v;   // exclusive
        offsets[i] = o;
        cursor[i] = o;
    }
}

// --- scatter: src indices sorted by dst ------------------------------------
__global__ __launch_bounds__(256) void k_scatter(const int* __restrict__ dst,
                                                 const int* __restrict__ srcix,
                                                 int* __restrict__ cursor,
                                                 int* __restrict__ src_sorted, int E)
{
    int e = blockIdx.x * 256 + threadIdx.x;
    if (e < E) {
        int d = dst[e];
        int pos = atomicAdd(&cursor[d], 1);
        src_sorted[pos] = srcix[e];
    }
}

// --- GEMM: H(bf16) = X(fp32) @ W + b, bf16 MFMA 16x16x32 -------------------
// R12: Wt staged to LDS in [nt][ks][t][q] 16B-slot layout. A wave's B-read
// for (nt,ks) is 64 lanes reading a permutation of 64 consecutive 16B slots.
// R15: epilogue stages the C-tile through LDS (WtL reused after a barrier):
// 32 scattered 2B stores -> 4 coalesced 1KB stores per wave.
__global__ __launch_bounds__(256) void k_gemm(const float* __restrict__ X,
                                              const unsigned short* __restrict__ Wt,
                                              const float* __restrict__ bvec,
                                              const float* __restrict__ u,
                                              const float* __restrict__ cvals,
                                              unsigned short* __restrict__ H,
                                              float* __restrict__ a_srcv,
                                              float* __restrict__ outX, int M)
{
    __shared__ unsigned short WtL[D * D];   // 32KB
    int tid = threadIdx.x;

    // cooperative stage: 2048 16B-chunks, 8 per thread, coalesced reads
    {
        const uint4* wsrc = (const uint4*)Wt;
        uint4* wdst = (uint4*)WtL;
#pragma unroll
        for (int i = 0; i < 8; ++i) {
            int idx = i * 256 + tid;           // 16B-chunk index
            int j = idx >> 4, k8 = idx & 15;
            wdst[((j >> 4) * 4 + (k8 >> 2)) * 64 + (j & 15) * 4 + (k8 & 3)] = wsrc[idx];
        }
    }

    int wave = tid >> 6;
    int lane = tid & 63;
    int q = lane >> 4;       // quad
    int t = lane & 15;
    int lof = t * 4 + q;     // lane's slot offset within a 64-slot group
    long mbase = (long)blockIdx.x * 64 + wave * 16;
    long row = mbase + t; if (row >= M) row = M - 1;   // clamp: dup writes ok
    const float* A = X + row * D;

    // issue ALL A-loads first — single exposed HBM latency for the wave
    float4 a[8];
#pragma unroll
    for (int ks = 0; ks < 4; ++ks) {
        int ko = ks * 32 + q * 8;
        a[2 * ks]     = *(const float4*)(A + ko);
        a[2 * ks + 1] = *(const float4*)(A + ko + 4);
    }

    // passthrough out_ing for rows above the scratch region
    if (row >= SPLIT_ROW) {
        float* O = outX + row * D;
#pragma unroll
        for (int ks = 0; ks < 4; ++ks) {
            int ko = ks * 32 + q * 8;
            *(float4*)(O + ko)     = a[2 * ks];
            *(float4*)(O + ko + 4) = a[2 * ks + 1];
        }
    }

    // a_src = x.u + c0 (each lane: 32-col slice; reduce across 4 quads)
    float adot = 0.f;
#pragma unroll
    for (int ks = 0; ks < 4; ++ks) {
        int ko = ks * 32 + q * 8;
        const float* up = u + ko;
        float4 fa = a[2 * ks], fb = a[2 * ks + 1];
        adot += fa.x*up[0] + fa.y*up[1] + fa.z*up[2] + fa.w*up[3]
              + fb.x*up[4] + fb.y*up[5] + fb.z*up[6] + fb.w*up[7];
    }
    adot += __shfl_xor(adot, 16); adot += __shfl_xor(adot, 32);
    if (q == 0) a_srcv[row] = adot + cvals[0];

    // bf16 A-fragments
    short8 af[4];
#pragma unroll
    for (int ks = 0; ks < 4; ++ks) {
        float4 fa = a[2 * ks], fb = a[2 * ks + 1];
        short8 f;
        f[0]=f2b(fa.x); f[1]=f2b(fa.y); f[2]=f2b(fa.z); f[3]=f2b(fa.w);
        f[4]=f2b(fb.x); f[5]=f2b(fb.y); f[6]=f2b(fb.z); f[7]=f2b(fb.w);
        af[ks] = f;
    }

    __syncthreads();   // Wt staging complete (placed late: staging overlaps A)

    f32x4 acc[8];
#pragma unroll
    for (int j = 0; j < 8; ++j) acc[j] = (f32x4){0.f, 0.f, 0.f, 0.f};

    const short8* WtS = (const short8*)WtL;
#pragma unroll
    for (int ks = 0; ks < 4; ++ks) {
#pragma unroll
        for (int nt = 0; nt < 8; ++nt) {
            short8 bfr = WtS[(nt * 4 + ks) * 64 + lof];
            acc[nt] = __builtin_amdgcn_mfma_f32_16x16x32_bf16(af[ks], bfr, acc[nt], 0, 0, 0);
        }
    }

    // --- epilogue: stage C-tile in LDS, store coalesced --------------------
    // C/D frag: col(n) = lane&15, row(m) = quad*4 + reg   [verified m89/m91]
    __syncthreads();   // all waves done reading WtL -> safe to reuse
    {
        unsigned short* myH = WtL + wave * 16 * D;   // private 4KB slice
#pragma unroll
        for (int r = 0; r < 4; ++r) {
#pragma unroll
            for (int nt = 0; nt < 8; ++nt) {
                myH[(q * 4 + r) * D + nt * 16 + t] = f2b(acc[nt][r] + bvec[nt * 16 + t]);
            }
        }
        // no barrier: wave reads back only its own slice (lgkmcnt orders it)
        const uint4* src4 = (const uint4*)myH;
#pragma unroll
        for (int i = 0; i < 4; ++i) {
            int idx = i * 64 + lane;                 // uint4 idx in 4KB slice
            long orow = mbase + i * 4 + (lane >> 4); // = (idx*16B)/256B
            if (orow < M) {
                *(uint4*)(H + orow * D + (lane & 15) * 8) = src4[idx];
            }
        }
    }
}

// --- per-dst: segment softmax + weighted agg + relu + residual -------------
// 4 dsts per wave (16-lane groups). R12/R15-proven: batch-0 H-rows prefetch
// before the softmax reduce chain; phase B is a 2-deep software pipeline
// with x4-padded unconditional loads (invalid lanes: mys=0 -> safe row-0
// load, myw=0 -> zero contribution).
__global__ __launch_bounds__(256) void k_agg(const int* __restrict__ offsets,
                                             const int* __restrict__ src_sorted,
                                             const float* __restrict__ a_src,
                                             const unsigned short* __restrict__ H,
                                             const float* __restrict__ x_taste,
                                             const float* __restrict__ v,
                                             const float* __restrict__ cvals,
                                             float* __restrict__ out_taste,
                                             int Nt)
{
    int wid  = (blockIdx.x * 256 + threadIdx.x) >> 6;   // global wave id
    int lane = threadIdx.x & 63;
    int g = lane >> 4, gl = lane & 15, gbase = g * 16;
    int d = wid * 4 + g;
    if (d >= Nt) return;

    int start = offsets[d], end = offsets[d + 1];
    int deg = end - start;
    bool has = gl < deg;

    // edge indices first: everything downstream hangs off these
    int mys = 0;
    if (has) mys = src_sorted[start + gl];

    // prefetch batch-0 H rows NOW — overlaps the entire softmax chain
    int ps0 = __shfl(mys, gbase + 0), ps1 = __shfl(mys, gbase + 1);
    int ps2 = __shfl(mys, gbase + 2), ps3 = __shfl(mys, gbase + 3);
    uint4 A0 = *(const uint4*)(H + (long)ps0 * D + gl * 8);
    uint4 A1 = *(const uint4*)(H + (long)ps1 * D + gl * 8);
    uint4 A2 = *(const uint4*)(H + (long)ps2 * D + gl * 8);
    uint4 A3 = *(const uint4*)(H + (long)ps3 * D + gl * 8);

    // x_taste row slice (8 floats/lane) -- reused for residual at the end
    const float* xrow = x_taste + (long)d * D + gl * 8;
    float4 xa = *(const float4*)xrow;
    float4 xb = *(const float4*)(xrow + 4);

    // a_dst = x_taste[d] . v + c1  (fused; group-local 16-lane xor reduce)
    const float* vp = v + gl * 8;
    float s = xa.x*vp[0] + xa.y*vp[1] + xa.z*vp[2] + xa.w*vp[3]
            + xb.x*vp[4] + xb.y*vp[5] + xb.z*vp[6] + xb.w*vp[7];
    s += __shfl_xor(s, 1); s += __shfl_xor(s, 2);
    s += __shfl_xor(s, 4); s += __shfl_xor(s, 8);
    float ad = s + cvals[1];

    // phase A: lane-parallel logits (first 16 edges held in registers)
    float myl = 0.f;
    if (has) {
        float l = a_src[mys] + ad;
        myl = l > 0.f ? l : 0.2f * l;
    }
    float m = has ? myl : -3.4e38f;
    for (int base = start + 16; base < end; base += 16) {   // deg>16: ~10%
        int e = base + gl;
        if (e < end) {
            float l = a_src[src_sorted[e]] + ad;
            l = l > 0.f ? l : 0.2f * l;
            m = fmaxf(m, l);
        }
    }
    m = fmaxf(m, __shfl_xor(m, 1)); m = fmaxf(m, __shfl_xor(m, 2));
    m = fmaxf(m, __shfl_xor(m, 4)); m = fmaxf(m, __shfl_xor(m, 8));

    float ssum = has ? __expf(myl - m) : 0.f;
    for (int base = start + 16; base < end; base += 16) {   // deg>16: ~10%
        int e = base + gl;
        if (e < end) {
            float l = a_src[src_sorted[e]] + ad;
            l = l > 0.f ? l : 0.2f * l;
            ssum += __expf(l - m);
        }
    }
    ssum += __shfl_xor(ssum, 1); ssum += __shfl_xor(ssum, 2);
    ssum += __shfl_xor(ssum, 4); ssum += __shfl_xor(ssum, 8);
    float inv = 1.0f / (ssum + 1e-16f);
    float myw = has ? __expf(myl - m) * inv : 0.f;

    // phase B: 2-deep pipelined gather-accumulate over x4-padded edges
    float acc[8];
#pragma unroll
    for (int j = 0; j < 8; ++j) acc[j] = 0.f;

    int dfirst = deg < 16 ? deg : 16;
    int dpad = (dfirst + 3) & ~3;          // 0,4,8,12,16

    for (int i = 0; i < dpad; i += 4) {
        float w0 = __shfl(myw, gbase + i),     w1 = __shfl(myw, gbase + i + 1);
        float w2 = __shfl(myw, gbase + i + 2), w3 = __shfl(myw, gbase + i + 3);
        int inext = i + 4;
        bool more = inext < dpad;
        uint4 B0, B1, B2, B3;
        if (more) {
            int t0 = __shfl(mys, gbase + inext),     t1 = __shfl(mys, gbase + inext + 1);
            int t2 = __shfl(mys, gbase + inext + 2), t3 = __shfl(mys, gbase + inext + 3);
            B0 = *(const uint4*)(H + (long)t0 * D + gl * 8);
            B1 = *(const uint4*)(H + (long)t1 * D + gl * 8);
            B2 = *(const uint4*)(H + (long)t2 * D + gl * 8);
            B3 = *(const uint4*)(H + (long)t3 * D + gl * 8);
        }
        acc8(acc, w0, A0); acc8(acc, w1, A1);
        acc8(acc, w2, A2); acc8(acc, w3, A3);
        if (more) { A0 = B0; A1 = B1; A2 = B2; A3 = B3; }
    }

    for (int e = start + 16; e < end; ++e) {                // deg>16 tail
        int s0 = src_sorted[e];
        float l = a_src[s0] + ad;
        l = l > 0.f ? l : 0.2f * l;
        float w0 = __expf(l - m) * inv;
        uint4 h0 = *(const uint4*)(H + (long)s0 * D + gl * 8);
        acc8(acc, w0, h0);
    }

    float4 oa, ob;
    oa.x = 0.5f * (fmaxf(acc[0], 0.f) + xa.x);
    oa.y = 0.5f * (fmaxf(acc[1], 0.f) + xa.y);
    oa.z = 0.5f * (fmaxf(acc[2], 0.f) + xa.z);
    oa.w = 0.5f * (fmaxf(acc[3], 0.f) + xa.w);
    ob.x = 0.5f * (fmaxf(acc[4], 0.f) + xb.x);
    ob.y = 0.5f * (fmaxf(acc[5], 0.f) + xb.y);
    ob.z = 0.5f * (fmaxf(acc[6], 0.f) + xb.z);
    ob.w = 0.5f * (fmaxf(acc[7], 0.f) + xb.w);
    float* orow = out_taste + (long)d * D + gl * 8;
    *(float4*)orow       = oa;
    *(float4*)(orow + 4) = ob;
}

// --- passthrough copy: out_ing rows [0, SPLIT_ROW) (16B/thread) ------------
__global__ __launch_bounds__(256) void k_copy(const uint4* __restrict__ src,
                                              uint4* __restrict__ dst, long n16)
{
    long i = (long)blockIdx.x * 256 + threadIdx.x;
    long stride = (long)gridDim.x * 256;
    for (; i < n16; i += stride) dst[i] = src[i];
}

extern "C" void kernel_launch(void* const* d_in, const int* in_sizes, int n_in,
                              void* d_out, int out_size, void* d_ws, size_t ws_size,
                              hipStream_t stream)
{
    const float* x_ing   = (const float*)d_in[0];
    const float* x_taste = (const float*)d_in[1];
    const float* W_ing   = (const float*)d_in[2];
    const float* b_ing   = (const float*)d_in[3];
    const float* W_taste = (const float*)d_in[4];
    const float* b_taste = (const float*)d_in[5];
    const float* att_src = (const float*)d_in[6];
    const float* att_dst = (const float*)d_in[7];
    // d_in[8..10] = Wk, bk, q: dead (softmax over single metapath == 1.0)
    const int* src_idx = (const int*)d_in[11];
    const int* dst_idx = (const int*)d_in[12];

    const int NI = in_sizes[0] / D;   // 100000
    const int NT = in_sizes[1] / D;   // 50000
    const int E  = in_sizes[11];      // 600000

    float* out = (float*)d_out;
    float* out_taste = out + (size_t)NI * D;               // region 1 (fp32)
    unsigned short* h_ing = (unsigned short*)d_out;        // bytes [0,25.6MB)

    // scratch inside d_out at byte offset 26MB (wiped by final x_ing copy).
    // d_ws is NOT used: harness re-poison races our pipeline (R7 forensics).
    char* ws = (char*)d_out + (size_t)26 * 1024 * 1024;
    size_t off = 0;
    auto alloc = [&](size_t bytes) -> void* {
        void* p = ws + off;
        off = (off + bytes + 255) & ~(size_t)255;
        return p;
    };
    float* a_src     = (float*)alloc((size_t)NI * 4);
    int* counts      = (int*)alloc((size_t)NT * 4);
    int* cursor      = (int*)alloc((size_t)NT * 4);
    int* offsets     = (int*)alloc((size_t)(NT + 1) * 4);
    int* src_sorted  = (int*)alloc((size_t)E * 4);
    unsigned short* Wt = (unsigned short*)alloc((size_t)D * D * 2);
    float* u         = (float*)alloc(D * 4);
    float* v         = (float*)alloc(D * 4);
    float* cvals     = (float*)alloc(2 * 4);
    int* blocksums   = (int*)alloc(256 * 4);
    int* blockpre    = (int*)alloc(256 * 4);
    (void)d_ws; (void)ws_size; (void)out_size; (void)n_in;
    // scratch ends < 29.7MB < SPLIT_ROW*512 = 31.46MB  (passthrough-safe)

    const int nb = (NT + 255) / 256;   // 196 scan blocks

    // prep also zeroes counts (blocks 129..129+nb)
    k_prep<<<129 + nb, 256, 0, stream>>>(W_ing, b_ing, W_taste, b_taste,
                                         att_src, att_dst, Wt, u, v, cvals,
                                         counts, NT);

    k_hist<<<(E + 255) / 256, 256, 0, stream>>>(dst_idx, counts, E);
    k_scanA<<<nb, 256, 0, stream>>>(counts, blocksums, NT);
    k_scanB<<<1, 256, 0, stream>>>(blocksums, blockpre, offsets, nb, NT);
    k_scanC<<<nb, 256, 0, stream>>>(counts, blockpre, offsets, cursor, NT);
    k_scatter<<<(E + 255) / 256, 256, 0, stream>>>(dst_idx, src_idx, cursor, src_sorted, E);

    // gemm fuses a_src AND passthrough stores for rows >= SPLIT_ROW
    k_gemm<<<(NI + 63) / 64, 256, 0, stream>>>(x_ing, Wt, b_ing, u, cvals,
                                               h_ing, a_src, out, NI);

    // agg fuses a_dst = x_taste.(W_taste att_dst) + b_taste.att_dst
    k_agg<<<(NT + 15) / 16, 256, 0, stream>>>(offsets, src_sorted, a_src,
                                              h_ing, x_taste, v, cvals,
                                              out_taste, NT);

    // out_ing rows [0, SPLIT_ROW) — LAST op, wipes h_ing staging + scratch
    long n16 = ((long)SPLIT_ROW * D * 4) / 16;
    k_copy<<<2048, 256, 0, stream>>>((const uint4*)x_ing, (uint4*)out, n16);
}